// Round 4
// baseline (570.220 us; speedup 1.0000x reference)
//
#include <hip/hip_runtime.h>
#include <math.h>

#define B_ 128
#define S_ 1024
#define D_ 512
#define H_ 512

typedef _Float16 f16x4 __attribute__((ext_vector_type(4)));
typedef _Float16 f16x8 __attribute__((ext_vector_type(8)));
typedef float    f32x4 __attribute__((ext_vector_type(4)));

#if defined(__has_builtin)
#if __has_builtin(__builtin_amdgcn_global_load_lds)
#define HAVE_GLDS 1
#endif
#endif
#ifndef HAVE_GLDS
#define HAVE_GLDS 0
#endif

// ---------------------------------------------------------------------------
__global__ void zero_k(float* __restrict__ p, int n) {
    int i = blockIdx.x * 256 + threadIdx.x;
    if (i < n) p[i] = 0.f;
}

// ---------------------------------------------------------------------------
// fp32 -> fp16 streaming convert, 8 elems/thread (32B read, 16B write)
__global__ __launch_bounds__(256) void cvt16_k(const float* __restrict__ src,
                                               _Float16* __restrict__ dst, int n8) {
    int i = blockIdx.x * 256 + threadIdx.x;
    if (i < n8) {
        float4 a = ((const float4*)src)[2 * i];
        float4 b = ((const float4*)src)[2 * i + 1];
        f16x8 r;
        r[0] = (_Float16)a.x; r[1] = (_Float16)a.y;
        r[2] = (_Float16)a.z; r[3] = (_Float16)a.w;
        r[4] = (_Float16)b.x; r[5] = (_Float16)b.y;
        r[6] = (_Float16)b.z; r[7] = (_Float16)b.w;
        *(f16x8*)(dst + (size_t)8 * i) = r;
    }
}

// ---------------------------------------------------------------------------
// out[b,h] = dot(X[b,:], W[h,:]) + bias[h]   (X:[B,D], W:[H,D], D=512)
__global__ __launch_bounds__(256) void linear_k(const float* __restrict__ X,
                                                const float* __restrict__ W,
                                                const float* __restrict__ bias,
                                                float* __restrict__ out) {
    int idx = blockIdx.x * 256 + threadIdx.x;
    int b = idx >> 9;
    int h = idx & 511;
    const float4* x = (const float4*)(X + (size_t)b * D_);
    const float4* w = (const float4*)(W + (size_t)h * D_);
    float s = 0.f;
#pragma unroll 8
    for (int k = 0; k < D_ / 4; ++k) {
        float4 xv = x[k], wv = w[k];
        s = fmaf(xv.x, wv.x, s);
        s = fmaf(xv.y, wv.y, s);
        s = fmaf(xv.z, wv.z, s);
        s = fmaf(xv.w, wv.w, s);
    }
    out[idx] = s + bias[h];
}

// ---------------------------------------------------------------------------
__device__ inline f16x8 cvt8(float4 a, float4 b) {   // RTN casts
    f16x8 r;
    r[0] = (_Float16)a.x; r[1] = (_Float16)a.y;
    r[2] = (_Float16)a.z; r[3] = (_Float16)a.w;
    r[4] = (_Float16)b.x; r[5] = (_Float16)b.y;
    r[6] = (_Float16)b.z; r[7] = (_Float16)b.w;
    return r;
}

// fast tanh: 1 - 2/(e^{2x}+1); exact limits at +/-inf
__device__ inline float fast_tanh(float x) {
    float e = __expf(2.f * x);
    return 1.f - 2.f / (e + 1.f);
}

// async global(per-lane addr) -> LDS(wave-uniform base + lane*16), 16B/lane
__device__ inline void stage16(const _Float16* g, _Float16* l, int lane) {
#if HAVE_GLDS
    __builtin_amdgcn_global_load_lds((__attribute__((address_space(1))) void*)g,
                                     (__attribute__((address_space(3))) void*)l,
                                     16, 0, 0);
#else
    f16x8 v = *(const f16x8*)g;
    *(f16x8*)((char*)l + lane * 16) = v;
#endif
}

// ---------------------------------------------------------------------------
// Score GEMM on pre-converted fp16 inputs. global_load_lds (16B) double-buffered
// staging, 1 barrier per K-step (barrier's implicit vmcnt(0) drains the DMA).
// LDS tiles [128][32] fp16 LINEAR (required by global_load_lds); both the DMA
// writes and ds_read_b128 fragment reads are at the 8-cycle bank floor.
// Grid (s=8, h=4, b): lid%8 = s-tile -> 4 h-blocks share ctx16 tile on one XCD L2.
// Epilogue: att[b,s] += sum_h V[h]*tanh(inp[b,h]+b_ctx[h]+acc)  (atomicAdd)
__global__ __launch_bounds__(256) void score16(const _Float16* __restrict__ ctx16,
                                               const _Float16* __restrict__ Wc16,
                                               const float* __restrict__ bc,
                                               const float* __restrict__ Vv,
                                               const float* __restrict__ inp,
                                               float* __restrict__ att) {
    __shared__ __align__(16) _Float16 Ah[2][128][32];
    __shared__ __align__(16) _Float16 Bh[2][128][32];
    __shared__ float red[8][128];

    const int tid = threadIdx.x;
    const int s0 = blockIdx.x * 128;   // s-blk fastest (XCD-aligned reuse)
    const int h0 = blockIdx.y * 128;
    const int b  = blockIdx.z;

    const int wave = tid >> 6;
    const int lane = tid & 63;
    const int wm = wave >> 1, wn = wave & 1;   // 2x2 wave grid (h x s)
    const int l15 = lane & 15, quad = lane >> 4;

    // DMA staging: wave covers rows wave*32 + j*16 + (lane>>2), k-granule lane&3
    const int rrow = lane >> 2;   // 0..15
    const int rgr  = lane & 3;    // 0..3
    const _Float16* Ag = Wc16 + (size_t)(h0 + wave * 32 + rrow) * D_ + rgr * 8;
    const _Float16* Bg = ctx16 + ((size_t)b * S_ + s0 + wave * 32 + rrow) * D_ + rgr * 8;

    f32x4 acc[4][4];
#pragma unroll
    for (int mi = 0; mi < 4; ++mi)
#pragma unroll
        for (int ni = 0; ni < 4; ++ni) acc[mi][ni] = (f32x4){0.f, 0.f, 0.f, 0.f};

#define STAGE(bf, k0) do {                                                      \
    stage16(Ag + (k0),            &Ah[bf][wave * 32][0],      lane);            \
    stage16(Ag + (k0) + 16 * D_,  &Ah[bf][wave * 32 + 16][0], lane);            \
    stage16(Bg + (k0),            &Bh[bf][wave * 32][0],      lane);            \
    stage16(Bg + (k0) + 16 * D_,  &Bh[bf][wave * 32 + 16][0], lane); } while (0)

#define COMPUTE(bf) do {                                                        \
    f16x8 bhf_[4];                                                              \
    _Pragma("unroll")                                                           \
    for (int ni = 0; ni < 4; ++ni)                                              \
        bhf_[ni] = *(const f16x8*)&Bh[bf][wn * 64 + ni * 16 + l15][quad * 8];   \
    _Pragma("unroll")                                                           \
    for (int mi = 0; mi < 4; ++mi) {                                            \
        f16x8 ah_ = *(const f16x8*)&Ah[bf][wm * 64 + mi * 16 + l15][quad * 8];  \
        _Pragma("unroll")                                                       \
        for (int ni = 0; ni < 4; ++ni)                                          \
            acc[mi][ni] = __builtin_amdgcn_mfma_f32_16x16x32_f16(ah_, bhf_[ni], \
                                                                 acc[mi][ni], 0, 0, 0); \
    } } while (0)

    STAGE(0, 0);
    __syncthreads();   // drains vmcnt(0): buf0 ready
#pragma unroll
    for (int it = 0; it < 16; ++it) {
        if (it + 1 < 16) STAGE((it + 1) & 1, (it + 1) * 32);  // DMA into idle buf
        COMPUTE(it & 1);                                      // overlaps the DMA
        __syncthreads();   // readers done + next-step DMA drained
    }
#undef STAGE
#undef COMPUTE

    // C/D layout: col(s)=l15, row(h)=quad*4+reg
    float p[4] = {0.f, 0.f, 0.f, 0.f};
#pragma unroll
    for (int mi = 0; mi < 4; ++mi) {
#pragma unroll
        for (int r = 0; r < 4; ++r) {
            const int h = h0 + wm * 64 + mi * 16 + quad * 4 + r;
            const float c  = inp[(size_t)b * H_ + h] + bc[h];
            const float vh = Vv[h];
#pragma unroll
            for (int ni = 0; ni < 4; ++ni)
                p[ni] = fmaf(vh, fast_tanh(c + acc[mi][ni][r]), p[ni]);
        }
    }
    const int cid = wm * 4 + quad;   // 8 h-contributors per s column
#pragma unroll
    for (int ni = 0; ni < 4; ++ni)
        red[cid][wn * 64 + ni * 16 + l15] = p[ni];
    __syncthreads();
    if (tid < 128) {
        float s = 0.f;
#pragma unroll
        for (int g = 0; g < 8; ++g) s += red[g][tid];
        atomicAdd(att + (size_t)b * S_ + s0 + tid, s);
    }
}

// ---------------------------------------------------------------------------
// fp32 fallback score (R3 engine: reg-staged, dbuf, XOR swizzle) for small ws.
__global__ __launch_bounds__(256) void score_f32(const float* __restrict__ ctx,
                                                 const float* __restrict__ Wc,
                                                 const float* __restrict__ bc,
                                                 const float* __restrict__ Vv,
                                                 const float* __restrict__ inp,
                                                 float* __restrict__ att) {
    __shared__ __align__(16) _Float16 Ah[2][128][32];
    __shared__ __align__(16) _Float16 Bh[2][128][32];
    __shared__ float red[8][128];

    const int tid = threadIdx.x;
    const int s0 = blockIdx.x * 128;
    const int h0 = blockIdx.y * 128;
    const int b  = blockIdx.z;

    const int r0  = tid >> 2;
    const int kg  = tid & 3;
    const int swz = ((kg ^ (r0 & 3)) << 3);

    const int wave = tid >> 6;
    const int lane = tid & 63;
    const int wm = wave >> 1, wn = wave & 1;
    const int l15 = lane & 15, quad = lane >> 4;
    const int rdsw = ((quad ^ (l15 & 3)) << 3);

    const float* Arow0 = Wc  + (size_t)(h0 + r0) * D_ + kg * 8;
    const float* Arow1 = Arow0 + (size_t)64 * D_;
    const float* Brow0 = ctx + ((size_t)b * S_ + s0 + r0) * D_ + kg * 8;
    const float* Brow1 = Brow0 + (size_t)64 * D_;

    f32x4 acc[4][4];
#pragma unroll
    for (int mi = 0; mi < 4; ++mi)
#pragma unroll
        for (int ni = 0; ni < 4; ++ni) acc[mi][ni] = (f32x4){0.f, 0.f, 0.f, 0.f};

    float4 A0a, A0b, A1a, A1b, B0a, B0b, B1a, B1b;

#define LOADS(step) do { const int kk_ = (step) * 32;                               \
    A0a = *(const float4*)(Arow0 + kk_); A0b = *(const float4*)(Arow0 + kk_ + 4);   \
    A1a = *(const float4*)(Arow1 + kk_); A1b = *(const float4*)(Arow1 + kk_ + 4);   \
    B0a = *(const float4*)(Brow0 + kk_); B0b = *(const float4*)(Brow0 + kk_ + 4);   \
    B1a = *(const float4*)(Brow1 + kk_); B1b = *(const float4*)(Brow1 + kk_ + 4); } while (0)

#define WRITE(bf) do {                                                              \
    *(f16x8*)&Ah[bf][r0][swz]      = cvt8(A0a, A0b);                                \
    *(f16x8*)&Ah[bf][r0 + 64][swz] = cvt8(A1a, A1b);                                \
    *(f16x8*)&Bh[bf][r0][swz]      = cvt8(B0a, B0b);                                \
    *(f16x8*)&Bh[bf][r0 + 64][swz] = cvt8(B1a, B1b); } while (0)

#define COMPUTE(bf) do {                                                            \
    f16x8 bhf_[4];                                                                  \
    _Pragma("unroll")                                                               \
    for (int ni = 0; ni < 4; ++ni)                                                  \
        bhf_[ni] = *(const f16x8*)&Bh[bf][wn * 64 + ni * 16 + l15][rdsw];           \
    _Pragma("unroll")                                                               \
    for (int mi = 0; mi < 4; ++mi) {                                                \
        f16x8 ah_ = *(const f16x8*)&Ah[bf][wm * 64 + mi * 16 + l15][rdsw];          \
        _Pragma("unroll")                                                           \
        for (int ni = 0; ni < 4; ++ni)                                              \
            acc[mi][ni] = __builtin_amdgcn_mfma_f32_16x16x32_f16(ah_, bhf_[ni],     \
                                                                 acc[mi][ni], 0, 0, 0); \
    } } while (0)

    LOADS(0);
    WRITE(0);
    LOADS(1);
    __syncthreads();

    for (int it = 0; it < 16; it += 2) {
        COMPUTE(0);
        WRITE(1);
        if (it + 2 < 16) LOADS(it + 2);
        __syncthreads();
        COMPUTE(1);
        if (it + 2 < 16) WRITE(0);
        if (it + 3 < 16) LOADS(it + 3);
        __syncthreads();
    }
#undef LOADS
#undef WRITE
#undef COMPUTE

    float p[4] = {0.f, 0.f, 0.f, 0.f};
#pragma unroll
    for (int mi = 0; mi < 4; ++mi) {
#pragma unroll
        for (int r = 0; r < 4; ++r) {
            const int h = h0 + wm * 64 + mi * 16 + quad * 4 + r;
            const float c  = inp[(size_t)b * H_ + h] + bc[h];
            const float vh = Vv[h];
#pragma unroll
            for (int ni = 0; ni < 4; ++ni)
                p[ni] = fmaf(vh, fast_tanh(c + acc[mi][ni][r]), p[ni]);
        }
    }
    const int cid = wm * 4 + quad;
#pragma unroll
    for (int ni = 0; ni < 4; ++ni)
        red[cid][wn * 64 + ni * 16 + l15] = p[ni];
    __syncthreads();
    if (tid < 128) {
        float s = 0.f;
#pragma unroll
        for (int g = 0; g < 8; ++g) s += red[g][tid];
        atomicAdd(att + (size_t)b * S_ + s0 + tid, s);
    }
}

// ---------------------------------------------------------------------------
__global__ __launch_bounds__(256) void softmax_k(const float* __restrict__ att,
                                                 const int* __restrict__ mask,
                                                 float* __restrict__ alpha) {
    const int b = blockIdx.x;
    const int t = threadIdx.x;
    __shared__ float sm[256];
    float v[4];
    float mx = -INFINITY;
#pragma unroll
    for (int i = 0; i < 4; ++i) {
        int s = t + i * 256;
        float a = att[(size_t)b * S_ + s];
        int mk = mask[(size_t)b * S_ + s];
        v[i] = mk ? -INFINITY : a;
        mx = fmaxf(mx, v[i]);
    }
    sm[t] = mx;
    __syncthreads();
    for (int off = 128; off > 0; off >>= 1) {
        if (t < off) sm[t] = fmaxf(sm[t], sm[t + off]);
        __syncthreads();
    }
    mx = sm[0];
    __syncthreads();
    float e[4];
    float sum = 0.f;
#pragma unroll
    for (int i = 0; i < 4; ++i) {
        e[i] = expf(v[i] - mx);
        sum += e[i];
    }
    sm[t] = sum;
    __syncthreads();
    for (int off = 128; off > 0; off >>= 1) {
        if (t < off) sm[t] += sm[t + off];
        __syncthreads();
    }
    float inv = 1.f / sm[0];
#pragma unroll
    for (int i = 0; i < 4; ++i) alpha[(size_t)b * S_ + t + i * 256] = e[i] * inv;
}

// ---------------------------------------------------------------------------
// out[b,:] += sum_{s in chunk} alpha[b,s] * src16[b,s,:]   (512-wide fp16 rows)
__global__ __launch_bounds__(256) void cbarh_k(const _Float16* __restrict__ src16,
                                               const float* __restrict__ alpha,
                                               float* __restrict__ out) {
    const int b  = blockIdx.y;
    const int s0 = blockIdx.x * 128;
    const int t  = threadIdx.x;
    const int w = t >> 6, lane = t & 63;
    __shared__ float al[128];
    __shared__ float red[3][512];
    if (t < 128) al[t] = alpha[(size_t)b * S_ + s0 + t];
    __syncthreads();
    const _Float16* base = src16 + ((size_t)b * S_ + s0) * D_ + lane * 8;
    float acc[8] = {0.f, 0.f, 0.f, 0.f, 0.f, 0.f, 0.f, 0.f};
#pragma unroll 4
    for (int s = w; s < 128; s += 4) {
        float a = al[s];
        f16x8 v = *(const f16x8*)(base + (size_t)s * D_);
#pragma unroll
        for (int j = 0; j < 8; ++j) acc[j] = fmaf(a, (float)v[j], acc[j]);
    }
    if (w > 0) {
#pragma unroll
        for (int j = 0; j < 8; ++j) red[w - 1][lane * 8 + j] = acc[j];
    }
    __syncthreads();
    if (w == 0) {
        float* dst = out + (size_t)b * D_ + lane * 8;
#pragma unroll
        for (int j = 0; j < 8; ++j)
            atomicAdd(dst + j, acc[j] + red[0][lane * 8 + j] + red[1][lane * 8 + j] + red[2][lane * 8 + j]);
    }
}

// ---------------------------------------------------------------------------
// fp32 fallback: cbar[b,:] += sum_{s in chunk} alpha[b,s] * context[b,s,:]
__global__ __launch_bounds__(256) void cbar_k(const float* __restrict__ ctx,
                                              const float* __restrict__ alpha,
                                              float* __restrict__ cbar) {
    const int b = blockIdx.y;
    const int s0 = blockIdx.x * 128;
    const int t = threadIdx.x;
    const int c4 = t & 127;
    const int sh = t >> 7;
    __shared__ float al[128];
    __shared__ float4 red[128];
    if (t < 128) al[t] = alpha[(size_t)b * S_ + s0 + t];
    __syncthreads();
    const float4* base = (const float4*)(ctx + ((size_t)b * S_ + s0) * D_);
    float4 c = {0.f, 0.f, 0.f, 0.f};
#pragma unroll 4
    for (int s = sh; s < 128; s += 2) {
        float a = al[s];
        float4 x = base[(size_t)s * (D_ / 4) + c4];
        c.x = fmaf(a, x.x, c.x);
        c.y = fmaf(a, x.y, c.y);
        c.z = fmaf(a, x.z, c.z);
        c.w = fmaf(a, x.w, c.w);
    }
    if (sh == 1) red[c4] = c;
    __syncthreads();
    if (sh == 0) {
        float4 o = red[c4];
        float* dst = cbar + (size_t)b * D_ + c4 * 4;
        atomicAdd(dst + 0, c.x + o.x);
        atomicAdd(dst + 1, c.y + o.y);
        atomicAdd(dst + 2, c.z + o.z);
        atomicAdd(dst + 3, c.w + o.w);
    }
}

// ---------------------------------------------------------------------------
extern "C" void kernel_launch(void* const* d_in, const int* in_sizes, int n_in,
                              void* d_out, int out_size, void* d_ws, size_t ws_size,
                              hipStream_t stream) {
    const float* input = (const float*)d_in[0];
    const float* ctx   = (const float*)d_in[1];
    const int*   mask  = (const int*)d_in[2];
    const float* W_in  = (const float*)d_in[3];
    const float* b_in  = (const float*)d_in[4];
    const float* W_ctx = (const float*)d_in[5];
    const float* b_ctx = (const float*)d_in[6];
    const float* V     = (const float*)d_in[7];

    float* hidden = (float*)d_out;
    float* alpha  = (float*)d_out + B_ * H_;

    float* inp  = (float*)d_ws;
    float* att  = inp + B_ * H_;
    float* cbar = att + B_ * S_;
    _Float16* ctx16 = (_Float16*)(cbar + B_ * D_);       // 1 MiB offset, 16B-aligned
    _Float16* Wc16  = ctx16 + (size_t)B_ * S_ * D_;      // +134.2 MB

    const size_t base_bytes = (size_t)(B_ * H_ + B_ * S_ + B_ * D_) * sizeof(float);
    const size_t f16_bytes  = ((size_t)B_ * S_ * D_ + (size_t)H_ * D_) * sizeof(_Float16);
    const bool big = ws_size >= base_bytes + f16_bytes;

    dim3 g2(S_ / 128, H_ / 128, B_);   // s fastest -> lid%8 = s-tile (XCD reuse)
    dim3 g4(S_ / 128, B_);
    const int nz = B_ * S_ + B_ * D_;  // att + cbar (contiguous)

    if (big) {
        zero_k<<<(nz + 255) / 256, 256, 0, stream>>>(att, nz);

        cvt16_k<<<(B_ * S_ * D_ / 8 + 255) / 256, 256, 0, stream>>>(ctx, ctx16, B_ * S_ * D_ / 8);
        cvt16_k<<<(H_ * D_ / 8 + 255) / 256, 256, 0, stream>>>(W_ctx, Wc16, H_ * D_ / 8);

        linear_k<<<(B_ * H_) / 256, 256, 0, stream>>>(input, W_in, b_in, inp);

        score16<<<g2, 256, 0, stream>>>(ctx16, Wc16, b_ctx, V, inp, att);

        softmax_k<<<B_, 256, 0, stream>>>(att, mask, alpha);

        cbarh_k<<<g4, 256, 0, stream>>>(ctx16, alpha, cbar);

        linear_k<<<(B_ * H_) / 256, 256, 0, stream>>>(cbar, W_ctx, b_ctx, hidden);
    } else {
        zero_k<<<(nz + 255) / 256, 256, 0, stream>>>(att, nz);

        linear_k<<<(B_ * H_) / 256, 256, 0, stream>>>(input, W_in, b_in, inp);

        score_f32<<<g2, 256, 0, stream>>>(ctx, W_ctx, b_ctx, V, inp, att);

        softmax_k<<<B_, 256, 0, stream>>>(att, mask, alpha);

        cbar_k<<<g4, 256, 0, stream>>>(ctx, alpha, cbar);

        linear_k<<<(B_ * H_) / 256, 256, 0, stream>>>(cbar, W_ctx, b_ctx, hidden);
    }
}

// Round 5
// 566.195 us; speedup vs baseline: 1.0071x; 1.0071x over previous
//
#include <hip/hip_runtime.h>
#include <math.h>

#define B_ 128
#define S_ 1024
#define D_ 512
#define H_ 512

typedef _Float16 f16x4 __attribute__((ext_vector_type(4)));
typedef _Float16 f16x8 __attribute__((ext_vector_type(8)));
typedef float    f32x4 __attribute__((ext_vector_type(4)));

#if defined(__has_builtin)
#if __has_builtin(__builtin_amdgcn_global_load_lds)
#define HAVE_GLDS 1
#endif
#endif
#ifndef HAVE_GLDS
#define HAVE_GLDS 0
#endif

// ---------------------------------------------------------------------------
__global__ void zero_k(float* __restrict__ p, int n) {
    int i = blockIdx.x * 256 + threadIdx.x;
    if (i < n) p[i] = 0.f;
}

// ---------------------------------------------------------------------------
// fp32 -> fp16 streaming convert, 8 elems/thread (32B read, 16B write)
__global__ __launch_bounds__(256) void cvt16_k(const float* __restrict__ src,
                                               _Float16* __restrict__ dst, int n8) {
    int i = blockIdx.x * 256 + threadIdx.x;
    if (i < n8) {
        float4 a = ((const float4*)src)[2 * i];
        float4 b = ((const float4*)src)[2 * i + 1];
        f16x8 r;
        r[0] = (_Float16)a.x; r[1] = (_Float16)a.y;
        r[2] = (_Float16)a.z; r[3] = (_Float16)a.w;
        r[4] = (_Float16)b.x; r[5] = (_Float16)b.y;
        r[6] = (_Float16)b.z; r[7] = (_Float16)b.w;
        *(f16x8*)(dst + (size_t)8 * i) = r;
    }
}

// ---------------------------------------------------------------------------
// out[b,h] = dot(X[b,:], W[h,:]) + bias[h]   (X:[B,D], W:[H,D], D=512)
__global__ __launch_bounds__(256) void linear_k(const float* __restrict__ X,
                                                const float* __restrict__ W,
                                                const float* __restrict__ bias,
                                                float* __restrict__ out) {
    int idx = blockIdx.x * 256 + threadIdx.x;
    int b = idx >> 9;
    int h = idx & 511;
    const float4* x = (const float4*)(X + (size_t)b * D_);
    const float4* w = (const float4*)(W + (size_t)h * D_);
    float s = 0.f;
#pragma unroll 8
    for (int k = 0; k < D_ / 4; ++k) {
        float4 xv = x[k], wv = w[k];
        s = fmaf(xv.x, wv.x, s);
        s = fmaf(xv.y, wv.y, s);
        s = fmaf(xv.z, wv.z, s);
        s = fmaf(xv.w, wv.w, s);
    }
    out[idx] = s + bias[h];
}

// ---------------------------------------------------------------------------
__device__ inline f16x8 cvt8(float4 a, float4 b) {   // RTN casts
    f16x8 r;
    r[0] = (_Float16)a.x; r[1] = (_Float16)a.y;
    r[2] = (_Float16)a.z; r[3] = (_Float16)a.w;
    r[4] = (_Float16)b.x; r[5] = (_Float16)b.y;
    r[6] = (_Float16)b.z; r[7] = (_Float16)b.w;
    return r;
}

// fast tanh: 1 - 2/(e^{2x}+1); exact limits at +/-inf
__device__ inline float fast_tanh(float x) {
    float e = __expf(2.f * x);
    return 1.f - 2.f / (e + 1.f);
}

// async global(per-lane addr) -> LDS(wave-uniform base + lane*16), 16B/lane
__device__ inline void stage16(const _Float16* g, _Float16* l, int lane) {
#if HAVE_GLDS
    __builtin_amdgcn_global_load_lds((__attribute__((address_space(1))) void*)g,
                                     (__attribute__((address_space(3))) void*)l,
                                     16, 0, 0);
#else
    f16x8 v = *(const f16x8*)g;
    *(f16x8*)((char*)l + lane * 16) = v;
#endif
}

// ---------------------------------------------------------------------------
// Score GEMM on pre-converted fp16 inputs. Triple-buffered global_load_lds
// staging with COUNTED vmcnt (T3+T4): stages issued 3 K-steps ahead, raw
// s_barrier (no vmcnt(0) drain), s_waitcnt vmcnt(8) in steady state.
// Pipeline safety: at iter k, outstanding = stages {k,k+1,k+2} = 12 wave-loads;
// vmcnt(8) retires stage k; post-compute barrier frees buf k%3 before
// STAGE(k+3) overwrites it. Tail: vmcnt(4) @k=14, vmcnt(0) @k=15.
// Grid (s=8, h=4, b): lid%8 = s-tile -> 4 h-blocks share ctx16 tile on one XCD L2.
// Epilogue: att[b,s] += sum_h V[h]*tanh(inp[b,h]+b_ctx[h]+acc)  (atomicAdd)
__global__ __launch_bounds__(256) void score16(const _Float16* __restrict__ ctx16,
                                               const _Float16* __restrict__ Wc16,
                                               const float* __restrict__ bc,
                                               const float* __restrict__ Vv,
                                               const float* __restrict__ inp,
                                               float* __restrict__ att) {
    __shared__ __align__(16) _Float16 Ah[3][128][32];
    __shared__ __align__(16) _Float16 Bh[3][128][32];
    __shared__ float red[8][128];

    const int tid = threadIdx.x;
    const int s0 = blockIdx.x * 128;   // s-blk fastest (XCD-aligned reuse)
    const int h0 = blockIdx.y * 128;
    const int b  = blockIdx.z;

    const int wave = tid >> 6;
    const int lane = tid & 63;
    const int wm = wave >> 1, wn = wave & 1;   // 2x2 wave grid (h x s)
    const int l15 = lane & 15, quad = lane >> 4;

    // DMA staging: wave covers rows wave*32 + (lane>>2), k-granule lane&3
    const int rrow = lane >> 2;   // 0..15
    const int rgr  = lane & 3;    // 0..3
    const _Float16* Ag = Wc16 + (size_t)(h0 + wave * 32 + rrow) * D_ + rgr * 8;
    const _Float16* Bg = ctx16 + ((size_t)b * S_ + s0 + wave * 32 + rrow) * D_ + rgr * 8;

    f32x4 acc[4][4];
#pragma unroll
    for (int mi = 0; mi < 4; ++mi)
#pragma unroll
        for (int ni = 0; ni < 4; ++ni) acc[mi][ni] = (f32x4){0.f, 0.f, 0.f, 0.f};

#define STAGE(bf, k0) do {                                                      \
    stage16(Ag + (k0),            &Ah[bf][wave * 32][0],      lane);            \
    stage16(Ag + (k0) + 16 * D_,  &Ah[bf][wave * 32 + 16][0], lane);            \
    stage16(Bg + (k0),            &Bh[bf][wave * 32][0],      lane);            \
    stage16(Bg + (k0) + 16 * D_,  &Bh[bf][wave * 32 + 16][0], lane); } while (0)

#define COMPUTE(bf) do {                                                        \
    f16x8 bhf_[4];                                                              \
    _Pragma("unroll")                                                           \
    for (int ni = 0; ni < 4; ++ni)                                              \
        bhf_[ni] = *(const f16x8*)&Bh[bf][wn * 64 + ni * 16 + l15][quad * 8];   \
    _Pragma("unroll")                                                           \
    for (int mi = 0; mi < 4; ++mi) {                                            \
        f16x8 ah_ = *(const f16x8*)&Ah[bf][wm * 64 + mi * 16 + l15][quad * 8];  \
        _Pragma("unroll")                                                       \
        for (int ni = 0; ni < 4; ++ni)                                          \
            acc[mi][ni] = __builtin_amdgcn_mfma_f32_16x16x32_f16(ah_, bhf_[ni], \
                                                                 acc[mi][ni], 0, 0, 0); \
    } } while (0)

    // prologue: fill the 3-deep pipeline (12 wave-loads in flight)
    STAGE(0, 0);
    STAGE(1, 32);
    STAGE(2, 64);

#pragma unroll
    for (int k = 0; k < 16; ++k) {
        __builtin_amdgcn_sched_barrier(0);
        if (k < 14)       asm volatile("s_waitcnt vmcnt(8)" ::: "memory");
        else if (k == 14) asm volatile("s_waitcnt vmcnt(4)" ::: "memory");
        else              asm volatile("s_waitcnt vmcnt(0)" ::: "memory");
        __builtin_amdgcn_s_barrier();     // everyone's stage(k) landed
        __builtin_amdgcn_sched_barrier(0);
        asm volatile("" ::: "memory");    // compiler fence: no ds_read hoisting
        __builtin_amdgcn_s_setprio(1);
        COMPUTE(k % 3);
        __builtin_amdgcn_s_setprio(0);
        __builtin_amdgcn_sched_barrier(0);
        __builtin_amdgcn_s_barrier();     // all waves done reading buf k%3
        asm volatile("" ::: "memory");
        if (k + 3 < 16) STAGE((k + 3) % 3, (k + 3) * 32);   // overwrite freed buf
    }
#undef STAGE
#undef COMPUTE

    // C/D layout: col(s)=l15, row(h)=quad*4+reg
    float p[4] = {0.f, 0.f, 0.f, 0.f};
#pragma unroll
    for (int mi = 0; mi < 4; ++mi) {
#pragma unroll
        for (int r = 0; r < 4; ++r) {
            const int h = h0 + wm * 64 + mi * 16 + quad * 4 + r;
            const float c  = inp[(size_t)b * H_ + h] + bc[h];
            const float vh = Vv[h];
#pragma unroll
            for (int ni = 0; ni < 4; ++ni)
                p[ni] = fmaf(vh, fast_tanh(c + acc[mi][ni][r]), p[ni]);
        }
    }
    const int cid = wm * 4 + quad;   // 8 h-contributors per s column
#pragma unroll
    for (int ni = 0; ni < 4; ++ni)
        red[cid][wn * 64 + ni * 16 + l15] = p[ni];
    __syncthreads();
    if (tid < 128) {
        float s = 0.f;
#pragma unroll
        for (int g = 0; g < 8; ++g) s += red[g][tid];
        atomicAdd(att + (size_t)b * S_ + s0 + tid, s);
    }
}

// ---------------------------------------------------------------------------
// fp32 fallback score (reg-staged, dbuf, XOR swizzle) for small ws.
__global__ __launch_bounds__(256) void score_f32(const float* __restrict__ ctx,
                                                 const float* __restrict__ Wc,
                                                 const float* __restrict__ bc,
                                                 const float* __restrict__ Vv,
                                                 const float* __restrict__ inp,
                                                 float* __restrict__ att) {
    __shared__ __align__(16) _Float16 Ah[2][128][32];
    __shared__ __align__(16) _Float16 Bh[2][128][32];
    __shared__ float red[8][128];

    const int tid = threadIdx.x;
    const int s0 = blockIdx.x * 128;
    const int h0 = blockIdx.y * 128;
    const int b  = blockIdx.z;

    const int r0  = tid >> 2;
    const int kg  = tid & 3;
    const int swz = ((kg ^ (r0 & 3)) << 3);

    const int wave = tid >> 6;
    const int lane = tid & 63;
    const int wm = wave >> 1, wn = wave & 1;
    const int l15 = lane & 15, quad = lane >> 4;
    const int rdsw = ((quad ^ (l15 & 3)) << 3);

    const float* Arow0 = Wc  + (size_t)(h0 + r0) * D_ + kg * 8;
    const float* Arow1 = Arow0 + (size_t)64 * D_;
    const float* Brow0 = ctx + ((size_t)b * S_ + s0 + r0) * D_ + kg * 8;
    const float* Brow1 = Brow0 + (size_t)64 * D_;

    f32x4 acc[4][4];
#pragma unroll
    for (int mi = 0; mi < 4; ++mi)
#pragma unroll
        for (int ni = 0; ni < 4; ++ni) acc[mi][ni] = (f32x4){0.f, 0.f, 0.f, 0.f};

    float4 A0a, A0b, A1a, A1b, B0a, B0b, B1a, B1b;

#define LOADS(step) do { const int kk_ = (step) * 32;                               \
    A0a = *(const float4*)(Arow0 + kk_); A0b = *(const float4*)(Arow0 + kk_ + 4);   \
    A1a = *(const float4*)(Arow1 + kk_); A1b = *(const float4*)(Arow1 + kk_ + 4);   \
    B0a = *(const float4*)(Brow0 + kk_); B0b = *(const float4*)(Brow0 + kk_ + 4);   \
    B1a = *(const float4*)(Brow1 + kk_); B1b = *(const float4*)(Brow1 + kk_ + 4); } while (0)

#define WRITE(bf) do {                                                              \
    *(f16x8*)&Ah[bf][r0][swz]      = cvt8(A0a, A0b);                                \
    *(f16x8*)&Ah[bf][r0 + 64][swz] = cvt8(A1a, A1b);                                \
    *(f16x8*)&Bh[bf][r0][swz]      = cvt8(B0a, B0b);                                \
    *(f16x8*)&Bh[bf][r0 + 64][swz] = cvt8(B1a, B1b); } while (0)

#define COMPUTE(bf) do {                                                            \
    f16x8 bhf_[4];                                                                  \
    _Pragma("unroll")                                                               \
    for (int ni = 0; ni < 4; ++ni)                                                  \
        bhf_[ni] = *(const f16x8*)&Bh[bf][wn * 64 + ni * 16 + l15][rdsw];           \
    _Pragma("unroll")                                                               \
    for (int mi = 0; mi < 4; ++mi) {                                                \
        f16x8 ah_ = *(const f16x8*)&Ah[bf][wm * 64 + mi * 16 + l15][rdsw];          \
        _Pragma("unroll")                                                           \
        for (int ni = 0; ni < 4; ++ni)                                              \
            acc[mi][ni] = __builtin_amdgcn_mfma_f32_16x16x32_f16(ah_, bhf_[ni],     \
                                                                 acc[mi][ni], 0, 0, 0); \
    } } while (0)

    LOADS(0);
    WRITE(0);
    LOADS(1);
    __syncthreads();

    for (int it = 0; it < 16; it += 2) {
        COMPUTE(0);
        WRITE(1);
        if (it + 2 < 16) LOADS(it + 2);
        __syncthreads();
        COMPUTE(1);
        if (it + 2 < 16) WRITE(0);
        if (it + 3 < 16) LOADS(it + 3);
        __syncthreads();
    }
#undef LOADS
#undef WRITE
#undef COMPUTE

    float p[4] = {0.f, 0.f, 0.f, 0.f};
#pragma unroll
    for (int mi = 0; mi < 4; ++mi) {
#pragma unroll
        for (int r = 0; r < 4; ++r) {
            const int h = h0 + wm * 64 + mi * 16 + quad * 4 + r;
            const float c  = inp[(size_t)b * H_ + h] + bc[h];
            const float vh = Vv[h];
#pragma unroll
            for (int ni = 0; ni < 4; ++ni)
                p[ni] = fmaf(vh, fast_tanh(c + acc[mi][ni][r]), p[ni]);
        }
    }
    const int cid = wm * 4 + quad;
#pragma unroll
    for (int ni = 0; ni < 4; ++ni)
        red[cid][wn * 64 + ni * 16 + l15] = p[ni];
    __syncthreads();
    if (tid < 128) {
        float s = 0.f;
#pragma unroll
        for (int g = 0; g < 8; ++g) s += red[g][tid];
        atomicAdd(att + (size_t)b * S_ + s0 + tid, s);
    }
}

// ---------------------------------------------------------------------------
__global__ __launch_bounds__(256) void softmax_k(const float* __restrict__ att,
                                                 const int* __restrict__ mask,
                                                 float* __restrict__ alpha) {
    const int b = blockIdx.x;
    const int t = threadIdx.x;
    __shared__ float sm[256];
    float v[4];
    float mx = -INFINITY;
#pragma unroll
    for (int i = 0; i < 4; ++i) {
        int s = t + i * 256;
        float a = att[(size_t)b * S_ + s];
        int mk = mask[(size_t)b * S_ + s];
        v[i] = mk ? -INFINITY : a;
        mx = fmaxf(mx, v[i]);
    }
    sm[t] = mx;
    __syncthreads();
    for (int off = 128; off > 0; off >>= 1) {
        if (t < off) sm[t] = fmaxf(sm[t], sm[t + off]);
        __syncthreads();
    }
    mx = sm[0];
    __syncthreads();
    float e[4];
    float sum = 0.f;
#pragma unroll
    for (int i = 0; i < 4; ++i) {
        e[i] = expf(v[i] - mx);
        sum += e[i];
    }
    sm[t] = sum;
    __syncthreads();
    for (int off = 128; off > 0; off >>= 1) {
        if (t < off) sm[t] += sm[t + off];
        __syncthreads();
    }
    float inv = 1.f / sm[0];
#pragma unroll
    for (int i = 0; i < 4; ++i) alpha[(size_t)b * S_ + t + i * 256] = e[i] * inv;
}

// ---------------------------------------------------------------------------
// out[b,:] += sum_{s in chunk} alpha[b,s] * src16[b,s,:]   (512-wide fp16 rows)
__global__ __launch_bounds__(256) void cbarh_k(const _Float16* __restrict__ src16,
                                               const float* __restrict__ alpha,
                                               float* __restrict__ out) {
    const int b  = blockIdx.y;
    const int s0 = blockIdx.x * 128;
    const int t  = threadIdx.x;
    const int w = t >> 6, lane = t & 63;
    __shared__ float al[128];
    __shared__ float red[3][512];
    if (t < 128) al[t] = alpha[(size_t)b * S_ + s0 + t];
    __syncthreads();
    const _Float16* base = src16 + ((size_t)b * S_ + s0) * D_ + lane * 8;
    float acc[8] = {0.f, 0.f, 0.f, 0.f, 0.f, 0.f, 0.f, 0.f};
#pragma unroll 4
    for (int s = w; s < 128; s += 4) {
        float a = al[s];
        f16x8 v = *(const f16x8*)(base + (size_t)s * D_);
#pragma unroll
        for (int j = 0; j < 8; ++j) acc[j] = fmaf(a, (float)v[j], acc[j]);
    }
    if (w > 0) {
#pragma unroll
        for (int j = 0; j < 8; ++j) red[w - 1][lane * 8 + j] = acc[j];
    }
    __syncthreads();
    if (w == 0) {
        float* dst = out + (size_t)b * D_ + lane * 8;
#pragma unroll
        for (int j = 0; j < 8; ++j)
            atomicAdd(dst + j, acc[j] + red[0][lane * 8 + j] + red[1][lane * 8 + j] + red[2][lane * 8 + j]);
    }
}

// ---------------------------------------------------------------------------
// fp32 fallback: cbar[b,:] += sum_{s in chunk} alpha[b,s] * context[b,s,:]
__global__ __launch_bounds__(256) void cbar_k(const float* __restrict__ ctx,
                                              const float* __restrict__ alpha,
                                              float* __restrict__ cbar) {
    const int b = blockIdx.y;
    const int s0 = blockIdx.x * 128;
    const int t = threadIdx.x;
    const int c4 = t & 127;
    const int sh = t >> 7;
    __shared__ float al[128];
    __shared__ float4 red[128];
    if (t < 128) al[t] = alpha[(size_t)b * S_ + s0 + t];
    __syncthreads();
    const float4* base = (const float4*)(ctx + ((size_t)b * S_ + s0) * D_);
    float4 c = {0.f, 0.f, 0.f, 0.f};
#pragma unroll 4
    for (int s = sh; s < 128; s += 2) {
        float a = al[s];
        float4 x = base[(size_t)s * (D_ / 4) + c4];
        c.x = fmaf(a, x.x, c.x);
        c.y = fmaf(a, x.y, c.y);
        c.z = fmaf(a, x.z, c.z);
        c.w = fmaf(a, x.w, c.w);
    }
    if (sh == 1) red[c4] = c;
    __syncthreads();
    if (sh == 0) {
        float4 o = red[c4];
        float* dst = cbar + (size_t)b * D_ + c4 * 4;
        atomicAdd(dst + 0, c.x + o.x);
        atomicAdd(dst + 1, c.y + o.y);
        atomicAdd(dst + 2, c.z + o.z);
        atomicAdd(dst + 3, c.w + o.w);
    }
}

// ---------------------------------------------------------------------------
extern "C" void kernel_launch(void* const* d_in, const int* in_sizes, int n_in,
                              void* d_out, int out_size, void* d_ws, size_t ws_size,
                              hipStream_t stream) {
    const float* input = (const float*)d_in[0];
    const float* ctx   = (const float*)d_in[1];
    const int*   mask  = (const int*)d_in[2];
    const float* W_in  = (const float*)d_in[3];
    const float* b_in  = (const float*)d_in[4];
    const float* W_ctx = (const float*)d_in[5];
    const float* b_ctx = (const float*)d_in[6];
    const float* V     = (const float*)d_in[7];

    float* hidden = (float*)d_out;
    float* alpha  = (float*)d_out + B_ * H_;

    float* inp  = (float*)d_ws;
    float* att  = inp + B_ * H_;
    float* cbar = att + B_ * S_;
    _Float16* ctx16 = (_Float16*)(cbar + B_ * D_);       // 1 MiB offset, 16B-aligned
    _Float16* Wc16  = ctx16 + (size_t)B_ * S_ * D_;      // +134.2 MB

    const size_t base_bytes = (size_t)(B_ * H_ + B_ * S_ + B_ * D_) * sizeof(float);
    const size_t f16_bytes  = ((size_t)B_ * S_ * D_ + (size_t)H_ * D_) * sizeof(_Float16);
    const bool big = ws_size >= base_bytes + f16_bytes;

    dim3 g2(S_ / 128, H_ / 128, B_);   // s fastest -> lid%8 = s-tile (XCD reuse)
    dim3 g4(S_ / 128, B_);
    const int nz = B_ * S_ + B_ * D_;  // att + cbar (contiguous)

    if (big) {
        zero_k<<<(nz + 255) / 256, 256, 0, stream>>>(att, nz);

        cvt16_k<<<(B_ * S_ * D_ / 8 + 255) / 256, 256, 0, stream>>>(ctx, ctx16, B_ * S_ * D_ / 8);
        cvt16_k<<<(H_ * D_ / 8 + 255) / 256, 256, 0, stream>>>(W_ctx, Wc16, H_ * D_ / 8);

        linear_k<<<(B_ * H_) / 256, 256, 0, stream>>>(input, W_in, b_in, inp);

        score16<<<g2, 256, 0, stream>>>(ctx16, Wc16, b_ctx, V, inp, att);

        softmax_k<<<B_, 256, 0, stream>>>(att, mask, alpha);

        cbarh_k<<<g4, 256, 0, stream>>>(ctx16, alpha, cbar);

        linear_k<<<(B_ * H_) / 256, 256, 0, stream>>>(cbar, W_ctx, b_ctx, hidden);
    } else {
        zero_k<<<(nz + 255) / 256, 256, 0, stream>>>(att, nz);

        linear_k<<<(B_ * H_) / 256, 256, 0, stream>>>(input, W_in, b_in, inp);

        score_f32<<<g2, 256, 0, stream>>>(ctx, W_ctx, b_ctx, V, inp, att);

        softmax_k<<<B_, 256, 0, stream>>>(att, mask, alpha);

        cbar_k<<<g4, 256, 0, stream>>>(ctx, alpha, cbar);

        linear_k<<<(B_ * H_) / 256, 256, 0, stream>>>(cbar, W_ctx, b_ctx, hidden);
    }
}